// Round 12
// baseline (84.322 us; speedup 1.0000x reference)
//
#include <hip/hip_runtime.h>
#include <math.h>

#define T_TOK 4096
#define DD 64
#define NHEADS 64          // B*H = 4*16
#define SEG 512            // tokens per landmark segment
#define SCALE 0.125f

// workspace layout (in floats)
#define QL_OFF   0                      // [64][8][64]
#define KL_OFF   32768                  // [64][8][64]
#define K2_OFF   65536                  // [64][8][8]
#define CS_OFF   69632                  // [64][8]
#define KP_OFF   70144                  // [4096][64]   k landmark partials (per 64-tok wave)
#define PA_OFF   332288                 // [4096][8][64] k3v partials (per 64-tok wave)
#define PD_OFF   2429440                // [4096][8]    denominators
#define W2_OFF   2462208                // [64][8][64]  pinv @ k3v
// end = 2494976 floats ~= 9.98 MB (<= proven ws size)

#define WAVE_BAR() __builtin_amdgcn_wave_barrier()

// ---------------------------------------------------------------------------
// 1. q landmarks: one block per (head, landmark) 512-token segment (512 blocks).
// ---------------------------------------------------------------------------
__global__ __launch_bounds__(256) void qsum_kernel(
    const float* __restrict__ q, float* __restrict__ ws) {
  int tid = threadIdx.x;
  const float4* q4 = (const float4*)q + (size_t)blockIdx.x * 8192;
  float4 b[2][8];
#pragma unroll
  for (int i = 0; i < 8; ++i) b[0][i] = q4[i * 256 + tid];
  float4 a = make_float4(0.f, 0.f, 0.f, 0.f);
#pragma unroll
  for (int j = 0; j < 4; ++j) {
    if (j < 3) {
#pragma unroll
      for (int i = 0; i < 8; ++i)
        b[(j + 1) & 1][i] = q4[(j + 1) * 2048 + i * 256 + tid];
    }
#pragma unroll
    for (int i = 0; i < 8; ++i) {
      float4 x = b[j & 1][i];
      a.x += x.x; a.y += x.y; a.z += x.z; a.w += x.w;
    }
  }
  __shared__ float4 red[16][17];
  red[tid >> 4][tid & 15] = a;
  __syncthreads();
  if (tid < 16) {
    float4 s = make_float4(0.f, 0.f, 0.f, 0.f);
#pragma unroll
    for (int g = 0; g < 16; ++g) {
      float4 r = red[g][tid];
      s.x += r.x; s.y += r.y; s.z += r.z; s.w += r.w;
    }
    const float inv = 1.f / (float)SEG;
    s.x *= inv; s.y *= inv; s.z *= inv; s.w *= inv;
    ((float4*)(ws + QL_OFF))[blockIdx.x * 16 + tid] = s;   // q_l directly
  }
}

// ---------------------------------------------------------------------------
// 2. kvpass v3: lane-slice dots + butterfly shuffle; k and v never touch LDS.
//    Wave = 64 contiguous tokens, 4 x 16-token tiles.  Lane = (t8 = lane>>3,
//    m8 = lane&7).  Per rep: lane loads k[t][8*m8..+7] (contiguous across the
//    wave), computes 8 partial dots vs qls[j] slices, shfl_xor(1,2,4)
//    butterfly -> full p-row on every lane; lanes m8<2 write the row to a
//    tiny wave-private pl.  Accumulate: v rows from global into registers,
//    acc[8] x float4 (static-indexed), pl read as broadcast b128.
//    Epilogue shfl reduces ksum/den/acc once.
// ---------------------------------------------------------------------------
__global__ __launch_bounds__(256) void kvpass_kernel(
    const float* __restrict__ k, const float* __restrict__ v,
    float* __restrict__ ws) {
  int tid = threadIdx.x;
  int w = tid >> 6, lane = tid & 63;
  int gw = blockIdx.x * 4 + w;            // 0..4095, 64 tokens each
  int hb = gw >> 6;
  int t8 = lane >> 3, m8 = lane & 7;
  int r0 = lane >> 4;
  __shared__ float qls[8][68];
  __shared__ float pl_all[4][16][12];     // wave-private p rows (48B stride)
  float (*pl)[12] = pl_all[w];

  if (tid < 128) {
    float4 x = ((const float4*)(ws + QL_OFF))[hb * 128 + tid];
    *(float4*)&qls[tid >> 4][(tid & 15) * 4] = x;
  }
  __syncthreads();   // the only block barrier (q_l staged)

  size_t base4 = (size_t)gw * 1024;       // 64 tokens x 16 float4
  const float4* k4 = (const float4*)k + base4;
  const float4* v4 = (const float4*)v + base4;

  float4 acc0 = make_float4(0.f,0.f,0.f,0.f), acc1 = make_float4(0.f,0.f,0.f,0.f);
  float4 acc2 = make_float4(0.f,0.f,0.f,0.f), acc3 = make_float4(0.f,0.f,0.f,0.f);
  float4 acc4 = make_float4(0.f,0.f,0.f,0.f), acc5 = make_float4(0.f,0.f,0.f,0.f);
  float4 acc6 = make_float4(0.f,0.f,0.f,0.f), acc7 = make_float4(0.f,0.f,0.f,0.f);
  float4 ksa = make_float4(0.f,0.f,0.f,0.f), ksb = make_float4(0.f,0.f,0.f,0.f);
  float den0=0.f,den1=0.f,den2=0.f,den3=0.f,den4=0.f,den5=0.f,den6=0.f,den7=0.f;

#pragma unroll 1
  for (int tile = 0; tile < 4; ++tile) {
    // v rows for the accumulate phase (coalesced; token i*4+r0, dims (lane&15)*4)
    float4 vb0 = v4[tile * 256 + lane];
    float4 vb1 = v4[tile * 256 + 64 + lane];
    float4 vb2 = v4[tile * 256 + 128 + lane];
    float4 vb3 = v4[tile * 256 + 192 + lane];
#pragma unroll
    for (int rep = 0; rep < 2; ++rep) {
      int t = rep * 8 + t8;
      float4 ka = k4[(tile * 16 + t) * 16 + m8 * 2];
      float4 kb = k4[(tile * 16 + t) * 16 + m8 * 2 + 1];
      ksa.x += ka.x; ksa.y += ka.y; ksa.z += ka.z; ksa.w += ka.w;
      ksb.x += kb.x; ksb.y += kb.y; ksb.z += kb.z; ksb.w += kb.w;
      float p[8];
#pragma unroll
      for (int j = 0; j < 8; ++j) {
        const float4* qr = (const float4*)&qls[j][m8 * 8];
        float4 qa = qr[0], qb = qr[1];
        float dp = ka.x*qa.x + ka.y*qa.y + ka.z*qa.z + ka.w*qa.w
                 + kb.x*qb.x + kb.y*qb.y + kb.z*qb.z + kb.w*qb.w;
        dp += __shfl_xor(dp, 1, 64);
        dp += __shfl_xor(dp, 2, 64);
        dp += __shfl_xor(dp, 4, 64);
        p[j] = __expf(dp * SCALE);
      }
      den0 += p[0]; den1 += p[1]; den2 += p[2]; den3 += p[3];
      den4 += p[4]; den5 += p[5]; den6 += p[6]; den7 += p[7];
      float4 lo = make_float4(p[0], p[1], p[2], p[3]);
      float4 hi = make_float4(p[4], p[5], p[6], p[7]);
      if (m8 == 0) *(float4*)&pl[t][0] = lo;
      if (m8 == 1) *(float4*)&pl[t][4] = hi;
    }
    WAVE_BAR();
    // accumulate: token t = i*4 + r0 matches vb[i]; pl reads broadcast
#pragma unroll
    for (int i = 0; i < 4; ++i) {
      int t = i * 4 + r0;
      float4 plo = *(const float4*)&pl[t][0];
      float4 phi = *(const float4*)&pl[t][4];
      float4 vv = (i == 0) ? vb0 : (i == 1) ? vb1 : (i == 2) ? vb2 : vb3;
      acc0.x += plo.x*vv.x; acc0.y += plo.x*vv.y; acc0.z += plo.x*vv.z; acc0.w += plo.x*vv.w;
      acc1.x += plo.y*vv.x; acc1.y += plo.y*vv.y; acc1.z += plo.y*vv.z; acc1.w += plo.y*vv.w;
      acc2.x += plo.z*vv.x; acc2.y += plo.z*vv.y; acc2.z += plo.z*vv.z; acc2.w += plo.z*vv.w;
      acc3.x += plo.w*vv.x; acc3.y += plo.w*vv.y; acc3.z += plo.w*vv.z; acc3.w += plo.w*vv.w;
      acc4.x += phi.x*vv.x; acc4.y += phi.x*vv.y; acc4.z += phi.x*vv.z; acc4.w += phi.x*vv.w;
      acc5.x += phi.y*vv.x; acc5.y += phi.y*vv.y; acc5.z += phi.y*vv.z; acc5.w += phi.y*vv.w;
      acc6.x += phi.z*vv.x; acc6.y += phi.z*vv.y; acc6.z += phi.z*vv.z; acc6.w += phi.z*vv.w;
      acc7.x += phi.w*vv.x; acc7.y += phi.w*vv.y; acc7.z += phi.w*vv.z; acc7.w += phi.w*vv.w;
    }
    WAVE_BAR();
  }
  // ksum: reduce over token-groups (lane bits 3,4,5) -> every lane has slice m8
  ksa.x += __shfl_xor(ksa.x, 8, 64); ksa.y += __shfl_xor(ksa.y, 8, 64);
  ksa.z += __shfl_xor(ksa.z, 8, 64); ksa.w += __shfl_xor(ksa.w, 8, 64);
  ksb.x += __shfl_xor(ksb.x, 8, 64); ksb.y += __shfl_xor(ksb.y, 8, 64);
  ksb.z += __shfl_xor(ksb.z, 8, 64); ksb.w += __shfl_xor(ksb.w, 8, 64);
  ksa.x += __shfl_xor(ksa.x, 16, 64); ksa.y += __shfl_xor(ksa.y, 16, 64);
  ksa.z += __shfl_xor(ksa.z, 16, 64); ksa.w += __shfl_xor(ksa.w, 16, 64);
  ksb.x += __shfl_xor(ksb.x, 16, 64); ksb.y += __shfl_xor(ksb.y, 16, 64);
  ksb.z += __shfl_xor(ksb.z, 16, 64); ksb.w += __shfl_xor(ksb.w, 16, 64);
  ksa.x += __shfl_xor(ksa.x, 32, 64); ksa.y += __shfl_xor(ksa.y, 32, 64);
  ksa.z += __shfl_xor(ksa.z, 32, 64); ksa.w += __shfl_xor(ksa.w, 32, 64);
  ksb.x += __shfl_xor(ksb.x, 32, 64); ksb.y += __shfl_xor(ksb.y, 32, 64);
  ksb.z += __shfl_xor(ksb.z, 32, 64); ksb.w += __shfl_xor(ksb.w, 32, 64);
  if (lane < 8) {
    ((float4*)(ws + KP_OFF))[gw * 16 + lane * 2] = ksa;
    ((float4*)(ws + KP_OFF))[gw * 16 + lane * 2 + 1] = ksb;
  }
  // den: identical within each group; reduce across groups (bits 3,4,5)
  den0 += __shfl_xor(den0, 8, 64); den1 += __shfl_xor(den1, 8, 64);
  den2 += __shfl_xor(den2, 8, 64); den3 += __shfl_xor(den3, 8, 64);
  den4 += __shfl_xor(den4, 8, 64); den5 += __shfl_xor(den5, 8, 64);
  den6 += __shfl_xor(den6, 8, 64); den7 += __shfl_xor(den7, 8, 64);
  den0 += __shfl_xor(den0, 16, 64); den1 += __shfl_xor(den1, 16, 64);
  den2 += __shfl_xor(den2, 16, 64); den3 += __shfl_xor(den3, 16, 64);
  den4 += __shfl_xor(den4, 16, 64); den5 += __shfl_xor(den5, 16, 64);
  den6 += __shfl_xor(den6, 16, 64); den7 += __shfl_xor(den7, 16, 64);
  den0 += __shfl_xor(den0, 32, 64); den1 += __shfl_xor(den1, 32, 64);
  den2 += __shfl_xor(den2, 32, 64); den3 += __shfl_xor(den3, 32, 64);
  den4 += __shfl_xor(den4, 32, 64); den5 += __shfl_xor(den5, 32, 64);
  den6 += __shfl_xor(den6, 32, 64); den7 += __shfl_xor(den7, 32, 64);
  if (lane == 0) {
    *(float4*)&ws[PD_OFF + (size_t)gw * 8] = make_float4(den0, den1, den2, den3);
    *(float4*)&ws[PD_OFF + (size_t)gw * 8 + 4] = make_float4(den4, den5, den6, den7);
  }
  // acc: reduce over r0 groups (lane bits 4,5); lanes 0..15 hold full (m, dims)
#define ACC_RED(A) \
  A.x += __shfl_xor(A.x, 16, 64); A.y += __shfl_xor(A.y, 16, 64); \
  A.z += __shfl_xor(A.z, 16, 64); A.w += __shfl_xor(A.w, 16, 64); \
  A.x += __shfl_xor(A.x, 32, 64); A.y += __shfl_xor(A.y, 32, 64); \
  A.z += __shfl_xor(A.z, 32, 64); A.w += __shfl_xor(A.w, 32, 64);
  ACC_RED(acc0) ACC_RED(acc1) ACC_RED(acc2) ACC_RED(acc3)
  ACC_RED(acc4) ACC_RED(acc5) ACC_RED(acc6) ACC_RED(acc7)
#undef ACC_RED
  if (lane < 16) {
    float4* pa = (float4*)(ws + PA_OFF) + (size_t)gw * 128;
    pa[0 * 16 + lane] = acc0;
    pa[1 * 16 + lane] = acc1;
    pa[2 * 16 + lane] = acc2;
    pa[3 * 16 + lane] = acc3;
    pa[4 * 16 + lane] = acc4;
    pa[5 * 16 + lane] = acc5;
    pa[6 * 16 + lane] = acc6;
    pa[7 * 16 + lane] = acc7;
  }
}

// ---------------------------------------------------------------------------
// 3. Reduce k partials -> k_l; kernel_2 softmax + column sums.
// ---------------------------------------------------------------------------
__global__ __launch_bounds__(512) void prepk_kernel(float* __restrict__ ws) {
  int hb = blockIdx.x, tid = threadIdx.x;
  __shared__ float qls[8][68];
  __shared__ float kls[8][68];
  __shared__ float ee[8][9];
  int m = tid >> 6, d = tid & 63;
  float s = 0.f;
#pragma unroll
  for (int j = 0; j < 8; ++j)
    s += ws[KP_OFF + (size_t)(hb * 64 + m * 8 + j) * 64 + d];
  s *= (1.f / (float)SEG);
  kls[m][d] = s;
  ws[KL_OFF + hb * 512 + tid] = s;
  qls[m][d] = ws[QL_OFF + hb * 512 + tid];
  __syncthreads();
  if (tid < 64) {
    int i = tid >> 3, j = tid & 7;
    float dot = 0.f;
#pragma unroll
    for (int dd = 0; dd < 64; ++dd) dot += qls[i][dd] * kls[j][dd];
    ee[i][j] = __expf(dot * SCALE);   // logits tiny: shift-free softmax safe
  }
  __syncthreads();
  if (tid < 64) {
    int i = tid >> 3, j = tid & 7;
    float ssum = 0.f;
#pragma unroll
    for (int jj = 0; jj < 8; ++jj) ssum += ee[i][jj];
    ws[K2_OFF + hb * 64 + tid] = ee[i][j] / ssum;
  }
  if (tid < 8) {
    float cs = 0.f;
    for (int ii = 0; ii < 8; ++ii) {
      float ssum = 0.f;
#pragma unroll
      for (int jj = 0; jj < 8; ++jj) ssum += ee[ii][jj];
      cs += ee[ii][tid] / ssum;
    }
    ws[CS_OFF + hb * 8 + tid] = cs;
  }
}

// ---------------------------------------------------------------------------
// 4. pinv (Newton-Schulz, global max over all 512 colsums) fused with
//    k3v reduce + W2 = pinv @ (k3v/den).  One 512-thr block per head.
// ---------------------------------------------------------------------------
__global__ __launch_bounds__(512) void pinvw2_kernel(float* __restrict__ ws) {
  int hb = blockIdx.x, tid = threadIdx.x;
  __shared__ float k3vs[8][68];
  __shared__ float K[8][9], V[8][9], X[8][9], Y[8][9];
  __shared__ float smax;
  int m = tid >> 6, d = tid & 63;
  float s = 0.f, den = 0.f;
  for (int c = 0; c < 64; ++c) {
    s += ws[PA_OFF + (((size_t)hb * 64 + c) * 8 + m) * 64 + d];
    den += ws[PD_OFF + ((size_t)hb * 64 + c) * 8 + m];
  }
  k3vs[m][d] = s / den;
  if (tid < 64) {
    float mx = 0.f;
    for (int t = 0; t < 8; ++t) mx = fmaxf(mx, ws[CS_OFF + t * 64 + tid]);
    for (int off = 32; off; off >>= 1) mx = fmaxf(mx, __shfl_xor(mx, off, 64));
    if (tid == 0) smax = mx;
  }
  int i = (tid >> 3) & 7, j = tid & 7;
  if (tid < 64) K[i][j] = ws[K2_OFF + hb * 64 + tid];
  __syncthreads();
  if (tid < 64) V[i][j] = K[j][i] * (1.f / smax);   // (1/max) * K^T
  __syncthreads();
  for (int it = 0; it < 6; ++it) {
    float x = 0.f;
    if (tid < 64) {
      for (int kk = 0; kk < 8; ++kk) x += K[i][kk] * V[kk][j];
      X[i][j] = x;
    }
    __syncthreads();
    float bm = 0.f;
    if (tid < 64) {
      for (int kk = 0; kk < 8; ++kk) bm += X[i][kk] * X[kk][j];
      bm = 7.f * x - bm;
      Y[i][j] = bm;
    }
    __syncthreads();
    float dm = 0.f;
    if (tid < 64) {
      for (int kk = 0; kk < 8; ++kk) dm += X[i][kk] * Y[kk][j];
      dm = 15.f * x - dm;
    }
    __syncthreads();
    if (tid < 64) Y[i][j] = dm;
    __syncthreads();
    float vd = 0.f;
    if (tid < 64) {
      for (int kk = 0; kk < 8; ++kk) vd += V[i][kk] * Y[kk][j];
      vd = 0.25f * (13.f * V[i][j] - vd);
    }
    __syncthreads();
    if (tid < 64) V[i][j] = vd;
    __syncthreads();
  }
  float o = 0.f;
#pragma unroll
  for (int jj = 0; jj < 8; ++jj) o += V[m][jj] * k3vs[jj][d];
  ws[W2_OFF + hb * 512 + tid] = o;
}

// ---------------------------------------------------------------------------
// 5. Output: barrier-free wave-private streaming.  Wave = 64 contiguous
//    tokens (4 x 16-token tiles).  klrow in VGPRs; W2 in private LDS.
// ---------------------------------------------------------------------------
__global__ __launch_bounds__(256) void out_kernel(
    const float* __restrict__ q, float* __restrict__ out,
    const float* __restrict__ ws) {
  int tid = threadIdx.x;
  int w = tid >> 6, lane = tid & 63;
  int gw = blockIdx.x * 4 + w;            // 0..4095, 64 tokens each
  int hb = gw >> 6;
  __shared__ float qt_all[4][16][68];
  __shared__ float pl_all[4][16][9];
  __shared__ float w2_all[4][8][68];
  float (*qt)[68] = qt_all[w];
  float (*pl)[9]  = pl_all[w];
  float (*w2)[68] = w2_all[w];

  int m = lane & 7;
  float4 klrow[16];
#pragma unroll
  for (int d4 = 0; d4 < 16; ++d4)
    klrow[d4] = ((const float4*)(ws + KL_OFF))[hb * 128 + m * 16 + d4];
#pragma unroll
  for (int i = 0; i < 2; ++i) {
    int f4 = i * 64 + lane;
    float4 y = ((const float4*)(ws + W2_OFF))[hb * 128 + f4];
    *(float4*)&w2[f4 >> 4][(f4 & 15) * 4] = y;
  }

  size_t base4 = (size_t)gw * 1024;       // 64 tokens x 16 float4
  const float4* q4 = (const float4*)q + base4;
  float4* o4 = (float4*)out + base4;
  float4 buf[2][4];
#pragma unroll
  for (int i = 0; i < 4; ++i) buf[0][i] = q4[i * 64 + lane];

#pragma unroll
  for (int tile = 0; tile < 4; ++tile) {
    int cur = tile & 1;
    if (tile < 3) {
#pragma unroll
      for (int i = 0; i < 4; ++i)
        buf[cur ^ 1][i] = q4[(tile + 1) * 256 + i * 64 + lane];
    }
#pragma unroll
    for (int i = 0; i < 4; ++i) {
      int f4 = i * 64 + lane;
      *(float4*)&qt[f4 >> 4][(f4 & 15) * 4] = buf[cur][i];
    }
    WAVE_BAR();
#pragma unroll
    for (int rep = 0; rep < 2; ++rep) {
      int t = rep * 8 + (lane >> 3);
      const float4* qr = (const float4*)&qt[t][0];
      float dot = 0.f;
#pragma unroll
      for (int d4 = 0; d4 < 16; ++d4) {
        float4 a = qr[d4];
        dot += a.x * klrow[d4].x + a.y * klrow[d4].y +
               a.z * klrow[d4].z + a.w * klrow[d4].w;
      }
      pl[t][m] = __expf(dot * SCALE);     // logits tiny: no max needed
    }
    WAVE_BAR();
#pragma unroll
    for (int i = 0; i < 4; ++i) {
      int t = i * 4 + (lane >> 4);
      int qd = lane & 15;
      float p0 = pl[t][0], p1 = pl[t][1], p2 = pl[t][2], p3 = pl[t][3];
      float p4 = pl[t][4], p5 = pl[t][5], p6 = pl[t][6], p7 = pl[t][7];
      float inv = 1.f / (p0 + p1 + p2 + p3 + p4 + p5 + p6 + p7);
      float4 acc = make_float4(0.f, 0.f, 0.f, 0.f);
      float pm[8] = {p0, p1, p2, p3, p4, p5, p6, p7};
#pragma unroll
      for (int m2 = 0; m2 < 8; ++m2) {
        float wgt = pm[m2] * inv;
        float4 wv = *(const float4*)&w2[m2][qd * 4];
        acc.x += wgt * wv.x; acc.y += wgt * wv.y;
        acc.z += wgt * wv.z; acc.w += wgt * wv.w;
      }
      o4[tile * 256 + i * 64 + lane] = acc;   // 1 KB coalesced store
    }
    WAVE_BAR();
  }
}

// ---------------------------------------------------------------------------
extern "C" void kernel_launch(void* const* d_in, const int* in_sizes, int n_in,
                              void* d_out, int out_size, void* d_ws, size_t ws_size,
                              hipStream_t stream) {
  const float* q = (const float*)d_in[0];
  const float* k = (const float*)d_in[1];
  const float* v = (const float*)d_in[2];
  float* out = (float*)d_out;
  float* ws = (float*)d_ws;

  qsum_kernel<<<512, 256, 0, stream>>>(q, ws);
  kvpass_kernel<<<1024, 256, 0, stream>>>(k, v, ws);
  prepk_kernel<<<NHEADS, 512, 0, stream>>>(ws);
  pinvw2_kernel<<<NHEADS, 512, 0, stream>>>(ws);
  out_kernel<<<1024, 256, 0, stream>>>(q, out, ws);
}